// Round 5
// baseline (60930.920 us; speedup 1.0000x reference)
//
#include <hip/hip_runtime.h>

#define BATCH  64
#define TT     512
#define IDIM   64
#define HDIM   512
#define NAHEAD 24
#define NWG    256

__device__ __forceinline__ float4 ld4(const float* p) {
  return *reinterpret_cast<const float4*>(p);
}
__device__ __forceinline__ float sigm(float x) { return 1.0f / (1.0f + expf(-x)); }

// Relaxed agent-scope access (global_load/store sc0 sc1): bypasses L1 +
// per-XCD L2; coherence point = memory-side L3. No cache-maintenance ops.
__device__ __forceinline__ float lda(const float* p) {
  return __hip_atomic_load(p, __ATOMIC_RELAXED, __HIP_MEMORY_SCOPE_AGENT);
}
__device__ __forceinline__ void sta(float* p, float v) {
  __hip_atomic_store(p, v, __ATOMIC_RELAXED, __HIP_MEMORY_SCOPE_AGENT);
}
__device__ __forceinline__ unsigned ldau(const unsigned* p) {
  return __hip_atomic_load(p, __ATOMIC_RELAXED, __HIP_MEMORY_SCOPE_AGENT);
}
__device__ __forceinline__ void stab(unsigned char* p, unsigned char v) {
  __hip_atomic_store(p, v, __ATOMIC_RELAXED, __HIP_MEMORY_SCOPE_AGENT);
}

// all 4 bytes of v satisfy wrap-safe (int8)(byte - tgt) >= 0
__device__ __forceinline__ int bytes_ge(unsigned v, unsigned tgt) {
  int ok = 1;
#pragma unroll
  for (int i = 0; i < 4; ++i) {
    int d = (int)((v >> (8 * i)) & 0xFF) - (int)tgt;
    ok &= (((d << 24) >> 24) >= 0);
  }
  return ok;
}

// Group barrier wait: 32 byte-flags in ONE 64B line (lanes 0..7 read 4B each).
// Caller must already have published its own flag >= tgt.
__device__ __forceinline__ void wait_group(const unsigned* __restrict__ fw,
                                           unsigned tgt, int tid) {
  if (tid < 64) {
    for (;;) {
      int ok = 1;
      if (tid < 8) ok = bytes_ge(ldau(fw + tid), tgt);
      if (__all(ok)) break;
      __builtin_amdgcn_s_sleep(1);
    }
  }
  __syncthreads();
}

// ---------------------------------------------------------------------------
// Persistent LSTM layer, batch-grouped: 256 WGs x 512 threads.
// Group bg = wg>>5 owns batch rows [bg*8, bg*8+8) — groups fully independent.
// Within a group, 32 WGs (wgl = wg&31) split H: WG owns h-cols
// [wgl*16, wgl*16+16) (= 64 gate-rows). Sync = 32-WG byte-flag barrier.
// Thread: b_loc = tid&7, ks = (tid>>3)&7 (K/8 slice), cg = tid>>6 (8 cols).
// 8 dots/thread -> LDS reduce. x-projection of t+1 overlaps the barrier.
// ---------------------------------------------------------------------------
template <int DIN>
__global__ __launch_bounds__(512, 2)
void lstm_layer(const float* __restrict__ in,   // [T][B][DIN] (cached)
                const float* __restrict__ w_ih, // [4H][DIN]   (cached)
                const float* __restrict__ w_hh, // [4H][H]     (cached)
                const float* __restrict__ b_ih, const float* __restrict__ b_hh,
                float* __restrict__ out_seq,    // [T][B][H]   (cached)
                float* __restrict__ h_buf,      // [2][B][H], slot0 zeroed (sc)
                float* __restrict__ hT, float* __restrict__ cT, // [B][H]
                unsigned char* __restrict__ flags)  // [8 groups][128B]
{
  const int tid   = threadIdx.x;
  const int wg    = blockIdx.x;
  const int bg    = wg >> 5;
  const int wgl   = wg & 31;
  const int b_loc = tid & 7;
  const int bglob = bg * 8 + b_loc;
  const int ks    = (tid >> 3) & 7;
  const int cg    = tid >> 6;          // wave index = col-group
  constexpr int K  = DIN + HDIM;
  constexpr int KS = K / 8;            // 72 (L0) / 128 (L1)
  const int k0 = ks * KS;

  __shared__ float part[64][8][9];     // [col][b][ks]
  __shared__ float gval[64][9];        // [col][b]

  // 8 consecutive gate-rows for this thread's col-group
  const int r0 = (cg >> 1) * HDIM + wgl * 16 + (cg & 1) * 8;
  const float* wihb = w_ih + (size_t)r0 * DIN;
  const float* whhb = w_hh + (size_t)r0 * HDIM;

  // reduce phase: thread reduces dot (col_r, b_loc)
  const int col_r = tid >> 3;          // 0..63
  const int r_r = (col_r >> 4) * HDIM + wgl * 16 + (col_r & 15);
  const float mybias = b_ih[r_r] + b_hh[r_r];

  // split this thread's k-range at the DIN boundary
  const int a0 = (k0 < DIN) ? k0 : DIN;
  const int a1 = (k0 + KS < DIN) ? k0 + KS : DIN;
  const int c0 = (k0 > DIN) ? k0 - DIN : 0;
  const int c1 = (k0 + KS > DIN) ? k0 + KS - DIN : 0;

  unsigned char* myflag = flags + bg * 128 + wgl;
  const unsigned* fw = (const unsigned*)(flags + bg * 128);

  float c_reg = 0.f;   // valid for tid<128: (hl = tid>>3, b_loc)
  float xacc[8];

  auto do_xpart = [&](int t) {         // cached, no recurrence dependence
    const float* xr = in + ((size_t)t * BATCH + bglob) * DIN;
#pragma unroll
    for (int d = 0; d < 8; ++d) xacc[d] = 0.f;
    for (int k = a0; k < a1; k += 4) {
      float4 x = ld4(xr + k);
#pragma unroll
      for (int d = 0; d < 8; ++d) {
        float4 w = ld4(wihb + (size_t)d * DIN + k);
        xacc[d] += x.x * w.x + x.y * w.y + x.z * w.z + x.w * w.w;
      }
    }
  };

  do_xpart(0);

  for (int t = 0; t < TT; ++t) {
    if (t > 0) wait_group(fw, (unsigned)(unsigned char)t, tid);

    const float* hprev = h_buf + (size_t)(t & 1) * (BATCH * HDIM) +
                         (size_t)bglob * HDIM;
    float* hnext = h_buf + (size_t)((t + 1) & 1) * (BATCH * HDIM);

    float acc[8];
#pragma unroll
    for (int d = 0; d < 8; ++d) acc[d] = xacc[d];

    for (int k = c0; k < c1; k += 4) {   // recurrent part (sc-bypass)
      float h0 = lda(hprev + k);
      float h1 = lda(hprev + k + 1);
      float h2 = lda(hprev + k + 2);
      float h3 = lda(hprev + k + 3);
#pragma unroll
      for (int d = 0; d < 8; ++d) {
        float4 w = ld4(whhb + (size_t)d * HDIM + k);
        acc[d] += h0 * w.x + h1 * w.y + h2 * w.z + h3 * w.w;
      }
    }

#pragma unroll
    for (int d = 0; d < 8; ++d) part[cg * 8 + d][b_loc][ks] = acc[d];
    __syncthreads();

    {
      float s = 0.f;
#pragma unroll
      for (int i = 0; i < 8; ++i) s += part[col_r][b_loc][i];
      gval[col_r][b_loc] = s + mybias;
    }
    __syncthreads();

    if (tid < 128) {
      const int hl = tid >> 3;           // 0..15
      const int hc = wgl * 16 + hl;
      float gi = gval[hl][b_loc];
      float gf = gval[16 + hl][b_loc];
      float gg = gval[32 + hl][b_loc];
      float go = gval[48 + hl][b_loc];
      float cn = sigm(gf) * c_reg + sigm(gi) * tanhf(gg);
      float hn = sigm(go) * tanhf(cn);
      c_reg = cn;
      sta(hnext + (size_t)bglob * HDIM + hc, hn);
      out_seq[((size_t)t * BATCH + bglob) * HDIM + hc] = hn;
      if (t == TT - 1) {
        hT[(size_t)bglob * HDIM + hc] = hn;
        cT[(size_t)bglob * HDIM + hc] = cn;
      }
    }
    __syncthreads();   // all waves drain vmcnt(0) before publish
    if (tid == 0) stab(myflag, (unsigned char)(t + 1));
    if (t + 1 < TT) do_xpart(t + 1);
  }
}

// ---------------------------------------------------------------------------
// x [B][T][I] -> xT [T][B][I] (I contiguous, pure permute copy)
// ---------------------------------------------------------------------------
__global__ __launch_bounds__(256)
void transpose_x(const float* __restrict__ x, float* __restrict__ xT)
{
  const int t  = blockIdx.x;
  const int i4 = (threadIdx.x & 15) * 4;
  const int b0 = threadIdx.x >> 4;
#pragma unroll
  for (int it = 0; it < 4; ++it) {
    int b = b0 + it * 16;
    float4 v = ld4(x + ((size_t)b * TT + t) * IDIM + i4);
    *reinterpret_cast<float4*>(xT + ((size_t)t * BATCH + b) * IDIM + i4) = v;
  }
}

// ---------------------------------------------------------------------------
// enc [T][B][H] -> encT [B][H][T] (64x64 (t,h) tiles per b, LDS pad 65)
// ---------------------------------------------------------------------------
__global__ __launch_bounds__(256)
void transpose_enc(const float* __restrict__ enc, float* __restrict__ encT)
{
  __shared__ float tile[64][65];
  const int b  = blockIdx.z;
  const int t0 = blockIdx.y * 64;
  const int h0 = blockIdx.x * 64;
  const int lane = threadIdx.x & 63;
  const int w    = threadIdx.x >> 6;
#pragma unroll
  for (int i = 0; i < 16; ++i) {
    int row = w + i * 4;
    tile[row][lane] = enc[((size_t)(t0 + row) * BATCH + b) * HDIM + h0 + lane];
  }
  __syncthreads();
#pragma unroll
  for (int i = 0; i < 16; ++i) {
    int row = w + i * 4;
    encT[((size_t)b * HDIM + h0 + row) * TT + t0 + lane] = tile[lane][row];
  }
}

// ---------------------------------------------------------------------------
// Persistent attention decoder, batch-grouped: 256 WGs x 512 threads.
// Group bg (8 b-rows) x 32 WGs; WG owns h/fc-cols [wgl*16, wgl*16+16).
// 3 group-barriers/step (scores, xi, h). Softmax computed redundantly per WG
// (no barrier). dec_in lives in registers (producer == consumer thread).
// ---------------------------------------------------------------------------
__global__ __launch_bounds__(512, 1)
void decoder_kernel(const float* __restrict__ enc,   // [T][B][H] (cached)
                    const float* __restrict__ encT,  // [B][H][T] (cached)
                    const float* __restrict__ w_ih, const float* __restrict__ w_hh,
                    const float* __restrict__ b_ih, const float* __restrict__ b_hh,
                    const float* __restrict__ w_fc, const float* __restrict__ b_fc,
                    const float* __restrict__ hT,    // [B][H] (cached)
                    const float* __restrict__ cT,    // [B][H] (cached)
                    float* __restrict__ hbuf,        // [2][B][H] (sc)
                    float* __restrict__ xi,          // [B][H]    (sc)
                    float* __restrict__ scores,      // [T][B]    (sc)
                    float* __restrict__ out,         // [B][24][C] (cached)
                    unsigned char* __restrict__ flags) // [8 groups][128B]
{
  const int tid   = threadIdx.x;
  const int wg    = blockIdx.x;
  const int bg    = wg >> 5;
  const int wgl   = wg & 31;
  const int b_loc = tid & 7;
  const int bglob = bg * 8 + b_loc;

  __shared__ float part[64][8][9];
  __shared__ float gval[64][9];
  __shared__ float pbuf[TT][9];       // softmax probs [t][b]
  __shared__ float red3[16][8][5];    // shared by P1/P3/P5 partials
  __shared__ float red64[64][9];      // softmax tree

  unsigned char* myflag = flags + bg * 128 + wgl;
  const unsigned* fw = (const unsigned*)(flags + bg * 128);
  unsigned bar = 0;
  auto barrier = [&]() {
    __syncthreads();
    ++bar;
    if (tid == 0) stab(myflag, (unsigned char)bar);
    wait_group(fw, bar, tid);
  };

  float c_reg = 0.f, dec_reg = 0.f;   // valid for tid<128: (tid>>3, b_loc)
  if (tid < 128) {
    int hl = tid >> 3;
    int hc = wgl * 16 + hl;
    sta(hbuf + (size_t)bglob * HDIM + hc, hT[(size_t)bglob * HDIM + hc]);
    c_reg = cT[(size_t)bglob * HDIM + hc];
  }
  barrier();

  for (int s = 0; s < NAHEAD; ++s) {
    const float* h_cur = hbuf + (size_t)(s & 1) * (BATCH * HDIM);
    float*       h_nxt = hbuf + (size_t)((s + 1) & 1) * (BATCH * HDIM);

    // ---- P1: scores[t][b], t in [wgl*16, wgl*16+16) ---------------------
    {
      const int tl  = (tid >> 3) & 15;
      const int ksl = tid >> 7;          // 0..3
      const int t = wgl * 16 + tl;
      const float* er = enc + ((size_t)t * BATCH + bglob) * HDIM;
      const float* hr = h_cur + (size_t)bglob * HDIM;
      float a = 0.f;
      for (int k = ksl * 128; k < ksl * 128 + 128; k += 4) {
        float4 e = ld4(er + k);
        a += e.x * lda(hr + k) + e.y * lda(hr + k + 1) +
             e.z * lda(hr + k + 2) + e.w * lda(hr + k + 3);
      }
      red3[tl][b_loc][ksl] = a;
    }
    __syncthreads();
    if (tid < 128) {
      int tl = tid >> 3;
      int t = wgl * 16 + tl;
      float sv = red3[tl][b_loc][0] + red3[tl][b_loc][1] +
                 red3[tl][b_loc][2] + red3[tl][b_loc][3];
      sta(scores + (size_t)t * BATCH + bglob, sv);
    }
    barrier();

    // ---- P2: softmax (redundant per WG, no barrier) -> pbuf -------------
    {
      const int tl = tid >> 3;           // 0..63
      float v[8];
#pragma unroll
      for (int i = 0; i < 8; ++i)
        v[i] = lda(scores + (size_t)(tl * 8 + i) * BATCH + bglob);
      float lm = v[0];
#pragma unroll
      for (int i = 1; i < 8; ++i) lm = fmaxf(lm, v[i]);
      red64[tl][b_loc] = lm;
      __syncthreads();
      for (int st = 32; st > 0; st >>= 1) {
        if (tl < st) red64[tl][b_loc] = fmaxf(red64[tl][b_loc], red64[tl + st][b_loc]);
        __syncthreads();
      }
      float m = red64[0][b_loc];
      __syncthreads();
      float lz = 0.f;
#pragma unroll
      for (int i = 0; i < 8; ++i) lz += expf(v[i] - m);
      red64[tl][b_loc] = lz;
      __syncthreads();
      for (int st = 32; st > 0; st >>= 1) {
        if (tl < st) red64[tl][b_loc] += red64[tl + st][b_loc];
        __syncthreads();
      }
      float rZ = 1.f / red64[0][b_loc];
#pragma unroll
      for (int i = 0; i < 8; ++i)
        pbuf[tl * 8 + i][b_loc] = expf(v[i] - m) * rZ;
    }
    __syncthreads();

    // ---- P3: ctx + dec_in -> xi -----------------------------------------
    {
      const int hl = (tid >> 3) & 15;
      const int ts = tid >> 7;
      const int hc = wgl * 16 + hl;
      const float* er = encT + ((size_t)bglob * HDIM + hc) * TT;
      float a = 0.f;
      for (int k = ts * 128; k < ts * 128 + 128; k += 4) {
        float4 e = ld4(er + k);
        a += pbuf[k][b_loc] * e.x + pbuf[k + 1][b_loc] * e.y +
             pbuf[k + 2][b_loc] * e.z + pbuf[k + 3][b_loc] * e.w;
      }
      red3[hl][b_loc][ts] = a;
    }
    __syncthreads();
    if (tid < 128) {
      int hl = tid >> 3;
      int hc = wgl * 16 + hl;
      float ctx = red3[hl][b_loc][0] + red3[hl][b_loc][1] +
                  red3[hl][b_loc][2] + red3[hl][b_loc][3];
      sta(xi + (size_t)bglob * HDIM + hc, ctx + dec_reg);
    }
    barrier();

    // ---- P4: gates (K=1024 concat xi;h), update c/h ---------------------
    {
      const int ksl = (tid >> 3) & 7;
      const int cg  = tid >> 6;
      const int k0  = ksl * 128;
      const int r0  = (cg >> 1) * HDIM + wgl * 16 + (cg & 1) * 8;
      float acc[8] = {0.f, 0.f, 0.f, 0.f, 0.f, 0.f, 0.f, 0.f};
      const float* vr = (ksl < 4) ? (xi + (size_t)bglob * HDIM + k0)
                                  : (h_cur + (size_t)bglob * HDIM + (k0 - HDIM));
      const float* wb = (ksl < 4) ? (w_ih + (size_t)r0 * HDIM + k0)
                                  : (w_hh + (size_t)r0 * HDIM + (k0 - HDIM));
      for (int k = 0; k < 128; k += 4) {
        float v0 = lda(vr + k), v1 = lda(vr + k + 1);
        float v2 = lda(vr + k + 2), v3 = lda(vr + k + 3);
#pragma unroll
        for (int d = 0; d < 8; ++d) {
          float4 w = ld4(wb + (size_t)d * HDIM + k);
          acc[d] += v0 * w.x + v1 * w.y + v2 * w.z + v3 * w.w;
        }
      }
#pragma unroll
      for (int d = 0; d < 8; ++d) part[cg * 8 + d][b_loc][ksl] = acc[d];
    }
    __syncthreads();
    {
      const int col = tid >> 3;
      const int r = (col >> 4) * HDIM + wgl * 16 + (col & 15);
      float sv = 0.f;
#pragma unroll
      for (int i = 0; i < 8; ++i) sv += part[col][b_loc][i];
      gval[col][b_loc] = sv + b_ih[r] + b_hh[r];
    }
    __syncthreads();
    if (tid < 128) {
      int hl = tid >> 3;
      int hc = wgl * 16 + hl;
      float gi = gval[hl][b_loc], gf = gval[16 + hl][b_loc];
      float gg = gval[32 + hl][b_loc], go = gval[48 + hl][b_loc];
      float cn = sigm(gf) * c_reg + sigm(gi) * tanhf(gg);
      float hn = sigm(go) * tanhf(cn);
      c_reg = cn;
      sta(h_nxt + (size_t)bglob * HDIM + hc, hn);
    }
    barrier();

    // ---- P5: pred = h @ w_fc^T + b_fc (WG-local, no barrier) ------------
    {
      const int cl  = (tid >> 3) & 15;
      const int ksl = tid >> 7;
      const int cc = wgl * 16 + cl;
      const float* wr = w_fc + (size_t)cc * HDIM;
      const float* hr = h_nxt + (size_t)bglob * HDIM;
      float a = 0.f;
      for (int k = ksl * 128; k < ksl * 128 + 128; k += 4) {
        float4 w = ld4(wr + k);
        a += w.x * lda(hr + k) + w.y * lda(hr + k + 1) +
             w.z * lda(hr + k + 2) + w.w * lda(hr + k + 3);
      }
      red3[cl][b_loc][ksl] = a;
    }
    __syncthreads();
    if (tid < 128) {
      int cl = tid >> 3;
      int cc = wgl * 16 + cl;
      float p = red3[cl][b_loc][0] + red3[cl][b_loc][1] +
                red3[cl][b_loc][2] + red3[cl][b_loc][3] + b_fc[cc];
      out[((size_t)bglob * NAHEAD + s) * HDIM + cc] = p;
      dec_reg = p;
    }
    __syncthreads();
  }
}

// ---------------------------------------------------------------------------
extern "C" void kernel_launch(void* const* d_in, const int* in_sizes, int n_in,
                              void* d_out, int out_size, void* d_ws, size_t ws_size,
                              hipStream_t stream) {
  const float* x     = (const float*)d_in[0];
  const float* w_ih0 = (const float*)d_in[1];
  const float* w_hh0 = (const float*)d_in[2];
  const float* b_ih0 = (const float*)d_in[3];
  const float* b_hh0 = (const float*)d_in[4];
  const float* w_ih1 = (const float*)d_in[5];
  const float* w_hh1 = (const float*)d_in[6];
  const float* b_ih1 = (const float*)d_in[7];
  const float* b_hh1 = (const float*)d_in[8];
  const float* w_ihd = (const float*)d_in[9];
  const float* w_hhd = (const float*)d_in[10];
  const float* b_ihd = (const float*)d_in[11];
  const float* b_hhd = (const float*)d_in[12];
  const float* w_fc  = (const float*)d_in[13];
  const float* b_fc  = (const float*)d_in[14];
  float* out = (float*)d_out;

  char* ws = (char*)d_ws;
  size_t off = 0;
  auto alloc = [&](size_t bytes) -> void* {
    void* p = ws + off;
    off += (bytes + 255) & ~(size_t)255;
    return p;
  };

  // ---- zero region (one memset) ----
  unsigned char* flags0 = (unsigned char*)alloc(8 * 128);
  unsigned char* flags1 = (unsigned char*)alloc(8 * 128);
  unsigned char* flagsD = (unsigned char*)alloc(8 * 128);
  float* hbuf0 = (float*)alloc(2 * BATCH * HDIM * 4);
  float* hbuf1 = (float*)alloc(2 * BATCH * HDIM * 4);
  const size_t zero_bytes = off;
  // ---- no-init scratch ----
  float* hT0   = (float*)alloc(BATCH * HDIM * 4);
  float* cT0   = (float*)alloc(BATCH * HDIM * 4);
  float* hT    = (float*)alloc(BATCH * HDIM * 4);
  float* cT    = (float*)alloc(BATCH * HDIM * 4);
  float* hbufD = (float*)alloc(2 * BATCH * HDIM * 4);
  float* xi    = (float*)alloc(BATCH * HDIM * 4);
  float* scores= (float*)alloc((size_t)TT * BATCH * 4);
  float* xT    = (float*)alloc((size_t)TT * BATCH * IDIM * 4);
  float* seq0  = (float*)alloc((size_t)TT * BATCH * HDIM * 4);
  float* enc   = (float*)alloc((size_t)TT * BATCH * HDIM * 4);
  float* encT  = (float*)alloc((size_t)BATCH * HDIM * TT * 4);
  (void)ws_size; (void)in_sizes; (void)n_in; (void)out_size;

  hipMemsetAsync(d_ws, 0, zero_bytes, stream);

  transpose_x<<<TT, 256, 0, stream>>>(x, xT);

  lstm_layer<IDIM><<<NWG, 512, 0, stream>>>(
      xT, w_ih0, w_hh0, b_ih0, b_hh0, seq0, hbuf0, hT0, cT0, flags0);

  lstm_layer<HDIM><<<NWG, 512, 0, stream>>>(
      seq0, w_ih1, w_hh1, b_ih1, b_hh1, enc, hbuf1, hT, cT, flags1);

  transpose_enc<<<dim3(8, 8, 64), 256, 0, stream>>>(enc, encT);

  decoder_kernel<<<NWG, 512, 0, stream>>>(
      enc, encT, w_ihd, w_hhd, b_ihd, b_hhd, w_fc, b_fc,
      hT, cT, hbufD, xi, scores, out, flagsD);
}

// Round 6
// 21191.220 us; speedup vs baseline: 2.8753x; 2.8753x over previous
//
#include <hip/hip_runtime.h>

#define BATCH  64
#define TT     512
#define IDIM   64
#define HDIM   512
#define NAHEAD 24
#define HB     (HDIM * BATCH)

__device__ __forceinline__ float4 ld4(const float* p) {
  return *reinterpret_cast<const float4*>(p);
}
__device__ __forceinline__ float sigm(float x) { return 1.0f / (1.0f + expf(-x)); }

// ---------------------------------------------------------------------------
// LSTM cell for 2 h-cols {j0, j0+1}, all 64 batch rows.
// Threads: 1024 = b(64) x gate(4) x kquarter(4). All layouts [.][B] so lane=b
// is coalesced; weight rows are wave-uniform (HW broadcast).
// sm: 4*4*2*64 floats (8 KB). Ends with __syncthreads (safe to call twice).
// ---------------------------------------------------------------------------
__device__ __forceinline__ void cell_tile2(
    int j0, const float* __restrict__ in0, int DIN0,   // [DIN0][B]
    const float* __restrict__ h_in,                    // [512][B]
    const float* __restrict__ w_ih,                    // [4H][DIN0]
    const float* __restrict__ w_hh,                    // [4H][512]
    const float* __restrict__ b_ih, const float* __restrict__ b_hh,
    float* __restrict__ c_state,                       // [512][B]
    float* __restrict__ h_out,                         // [512][B]
    float* sm)
{
  const int tid = threadIdx.x;
  const int b  = tid & 63;
  const int g  = (tid >> 6) & 3;
  const int kq = tid >> 8;
  const int K  = DIN0 + HDIM;
  const int KQ = K >> 2;
  const int k0 = kq * KQ, k1 = k0 + KQ;
  // split this thread's k-range at the DIN0 boundary (all bounds %4 == 0)
  const int a0 = (k0 < DIN0) ? k0 : DIN0;
  const int a1 = (k1 < DIN0) ? k1 : DIN0;
  const int c0 = (k0 > DIN0) ? k0 - DIN0 : 0;
  const int c1 = (k1 > DIN0) ? k1 - DIN0 : 0;

  const float* wi0 = w_ih + (size_t)(g * HDIM + j0) * DIN0;
  const float* wi1 = wi0 + DIN0;
  const float* wh0 = w_hh + (size_t)(g * HDIM + j0) * HDIM;
  const float* wh1 = wh0 + HDIM;

  float acc0 = 0.f, acc1 = 0.f;
#pragma unroll 2
  for (int k = a0; k < a1; k += 4) {
    float x0 = in0[(k + 0) * BATCH + b];
    float x1 = in0[(k + 1) * BATCH + b];
    float x2 = in0[(k + 2) * BATCH + b];
    float x3 = in0[(k + 3) * BATCH + b];
    float4 wa = ld4(wi0 + k), wb = ld4(wi1 + k);
    acc0 += x0 * wa.x + x1 * wa.y + x2 * wa.z + x3 * wa.w;
    acc1 += x0 * wb.x + x1 * wb.y + x2 * wb.z + x3 * wb.w;
  }
#pragma unroll 2
  for (int k = c0; k < c1; k += 4) {
    float h0 = h_in[(k + 0) * BATCH + b];
    float h1 = h_in[(k + 1) * BATCH + b];
    float h2 = h_in[(k + 2) * BATCH + b];
    float h3 = h_in[(k + 3) * BATCH + b];
    float4 wa = ld4(wh0 + k), wb = ld4(wh1 + k);
    acc0 += h0 * wa.x + h1 * wa.y + h2 * wa.z + h3 * wa.w;
    acc1 += h0 * wb.x + h1 * wb.y + h2 * wb.z + h3 * wb.w;
  }
  sm[((kq * 4 + g) * 2 + 0) * 64 + b] = acc0;   // lane=b stride 1: conflict-free
  sm[((kq * 4 + g) * 2 + 1) * 64 + b] = acc1;
  __syncthreads();

  if (tid < 128) {
    const int bb = tid & 63, cl = tid >> 6;
    const int jc = j0 + cl;
    float gv[4];
#pragma unroll
    for (int gg = 0; gg < 4; ++gg) {
      float s = 0.f;
#pragma unroll
      for (int q = 0; q < 4; ++q) s += sm[((q * 4 + gg) * 2 + cl) * 64 + bb];
      int r = gg * HDIM + jc;
      gv[gg] = s + b_ih[r] + b_hh[r];
    }
    float cold = c_state[(size_t)jc * BATCH + bb];
    float cn = sigm(gv[1]) * cold + sigm(gv[0]) * tanhf(gv[2]);   // f,i,g
    float hn = sigm(gv[3]) * tanhf(cn);                           // o
    c_state[(size_t)jc * BATCH + bb] = cn;
    h_out[(size_t)jc * BATCH + bb] = hn;
  }
  __syncthreads();   // smem safe for reuse by a second phase
}

// ---------------------------------------------------------------------------
// One pipeline step: L0 at time t (if t<T) and L1 at time t-1 (if t>=1).
// seq0[tau] = h0_{tau-1} (slot0 = zeros); enc[tau] = h1_{tau-1} (slot0 = 0).
// No intra-kernel cross-WG dependency: L0 writes seq0[t+1], L1 reads seq0[t].
// ---------------------------------------------------------------------------
__global__ __launch_bounds__(1024, 1)
void lstm_step(int t,
               const float* __restrict__ xT,    // [T][I][B]
               const float* __restrict__ w_ih0, const float* __restrict__ w_hh0,
               const float* __restrict__ b_ih0, const float* __restrict__ b_hh0,
               const float* __restrict__ w_ih1, const float* __restrict__ w_hh1,
               const float* __restrict__ b_ih1, const float* __restrict__ b_hh1,
               float* __restrict__ seq0,        // [T+1][H][B]
               float* __restrict__ enc,         // [T+1][H][B]
               float* __restrict__ cst0, float* __restrict__ cst1)  // [H][B]
{
  __shared__ float sm[4 * 4 * 2 * 64];
  const int j0 = blockIdx.x * 2;
  if (t < TT)
    cell_tile2(j0, xT + (size_t)t * IDIM * BATCH, IDIM,
               seq0 + (size_t)t * HB,
               w_ih0, w_hh0, b_ih0, b_hh0,
               cst0, seq0 + (size_t)(t + 1) * HB, sm);
  if (t >= 1)
    cell_tile2(j0, seq0 + (size_t)t * HB, HDIM,
               enc + (size_t)(t - 1) * HB,
               w_ih1, w_hh1, b_ih1, b_hh1,
               cst1, enc + (size_t)t * HB, sm);
}

// ---------------------------------------------------------------------------
// Decoder gate step (xi ; h_cur) -> h_out, c in place. 256 WGs x 1024.
// ---------------------------------------------------------------------------
__global__ __launch_bounds__(1024, 1)
void dec_gates(const float* __restrict__ xi, const float* __restrict__ h_cur,
               const float* __restrict__ w_ih, const float* __restrict__ w_hh,
               const float* __restrict__ b_ih, const float* __restrict__ b_hh,
               float* __restrict__ cst, float* __restrict__ h_out)
{
  __shared__ float sm[4 * 4 * 2 * 64];
  cell_tile2(blockIdx.x * 2, xi, HDIM, h_cur, w_ih, w_hh, b_ih, b_hh,
             cst, h_out, sm);
}

// ---------------------------------------------------------------------------
// scores[t][b] = dot(enc_out[t][.][b], h_cur[.][b]); WG handles 2 t's.
// ---------------------------------------------------------------------------
__global__ __launch_bounds__(512, 2)
void attn_scores(const float* __restrict__ enc,   // [T+1][H][B]
                 const float* __restrict__ h_cur, // [H][B]
                 float* __restrict__ scores)      // [T][B]
{
  __shared__ float red[2][8][64];
  const int tid = threadIdx.x;
  const int b  = tid & 63;
  const int ks = tid >> 6;              // 0..7, k-slice of 64
  const int t0 = blockIdx.x * 2;
  const float* e0 = enc + (size_t)(t0 + 1) * HB + ks * 64 * BATCH;
  const float* e1 = e0 + HB;
  const float* hr = h_cur + ks * 64 * BATCH;
  float a0 = 0.f, a1 = 0.f;
#pragma unroll 4
  for (int k = 0; k < 64; ++k) {
    float hv = hr[k * BATCH + b];
    a0 += hv * e0[k * BATCH + b];
    a1 += hv * e1[k * BATCH + b];
  }
  red[0][ks][b] = a0;
  red[1][ks][b] = a1;
  __syncthreads();
  if (tid < 128) {
    int tl = tid >> 6;
    float s = 0.f;
#pragma unroll
    for (int i = 0; i < 8; ++i) s += red[tl][i][b];
    scores[(size_t)(t0 + tl) * BATCH + b] = s;
  }
}

// ---------------------------------------------------------------------------
// Per step s: redundant per-WG softmax over scores, ctx for 2 h-cols,
// pred_{s-1} = h_cur @ w_fc^T (rows = same 2 cols) -> out row s-1,
// xi = ctx + pred_{s-1} (dec_in). s==0: dec_in = 0, no out write.
// ---------------------------------------------------------------------------
__global__ __launch_bounds__(512, 2)
void attn_ctx(const float* __restrict__ enc,     // [T+1][H][B]
              const float* __restrict__ scores,  // [T][B]
              const float* __restrict__ h_cur,   // [H][B]
              const float* __restrict__ w_fc, const float* __restrict__ b_fc,
              float* __restrict__ xi,            // [H][B]
              float* __restrict__ out,           // [B][24][C]
              int s)
{
  __shared__ float red[8][2][64];
  __shared__ float mz[2][64];
  __shared__ float ctxv[2][64];
  const int tid = threadIdx.x;
  const int b  = tid & 63;
  const int ts = tid >> 6;              // 0..7, t-slice of 64
  const int hc0 = blockIdx.x * 2;

  // softmax stats (redundant per WG — avoids a device-wide barrier)
  float m = -1e30f;
  for (int t = ts * 64; t < ts * 64 + 64; ++t)
    m = fmaxf(m, scores[(size_t)t * BATCH + b]);
  red[ts][0][b] = m;
  __syncthreads();
  if (tid < 64) {
    float mm = red[0][0][b];
#pragma unroll
    for (int i = 1; i < 8; ++i) mm = fmaxf(mm, red[i][0][b]);
    mz[0][b] = mm;
  }
  __syncthreads();
  m = mz[0][b];
  float z = 0.f;
  for (int t = ts * 64; t < ts * 64 + 64; ++t)
    z += expf(scores[(size_t)t * BATCH + b] - m);
  red[ts][1][b] = z;
  __syncthreads();
  if (tid < 64) {
    float zz = 0.f;
#pragma unroll
    for (int i = 0; i < 8; ++i) zz += red[i][1][b];
    mz[1][b] = 1.f / zz;
  }
  __syncthreads();
  const float rZ = mz[1][b];

  // ctx for cols hc0, hc0+1 over this thread's t-slice
  float a0 = 0.f, a1 = 0.f;
  const float* eb = enc + HB + (size_t)hc0 * BATCH + b;
  for (int t = ts * 64; t < ts * 64 + 64; ++t) {
    float p = expf(scores[(size_t)t * BATCH + b] - m) * rZ;
    a0 += p * eb[(size_t)t * HB];
    a1 += p * eb[(size_t)t * HB + BATCH];
  }
  __syncthreads();
  red[ts][0][b] = a0;
  red[ts][1][b] = a1;
  __syncthreads();
  if (tid < 128) {
    int cl = tid >> 6;
    float c = 0.f;
#pragma unroll
    for (int i = 0; i < 8; ++i) c += red[i][cl][b];
    ctxv[cl][b] = c;
  }

  // pred_{s-1} for rows hc0, hc0+1 (k-sliced)
  float p0 = 0.f, p1 = 0.f;
  if (s >= 1) {
    const float* w0 = w_fc + (size_t)hc0 * HDIM + ts * 64;
    const float* w1 = w0 + HDIM;
    const float* hr = h_cur + ts * 64 * BATCH;
#pragma unroll 2
    for (int k = 0; k < 64; k += 4) {
      float4 wa = ld4(w0 + k), wb = ld4(w1 + k);
      float h0 = hr[(k + 0) * BATCH + b], h1 = hr[(k + 1) * BATCH + b];
      float h2 = hr[(k + 2) * BATCH + b], h3 = hr[(k + 3) * BATCH + b];
      p0 += wa.x * h0 + wa.y * h1 + wa.z * h2 + wa.w * h3;
      p1 += wb.x * h0 + wb.y * h1 + wb.z * h2 + wb.w * h3;
    }
  }
  __syncthreads();
  red[ts][0][b] = p0;
  red[ts][1][b] = p1;
  __syncthreads();
  if (tid < 128) {
    int cl = tid >> 6;
    int cc = hc0 + cl;
    float pred = 0.f;
    if (s >= 1) {
#pragma unroll
      for (int i = 0; i < 8; ++i) pred += red[i][cl][b];
      pred += b_fc[cc];
      out[((size_t)b * NAHEAD + (s - 1)) * HDIM + cc] = pred;
    }
    xi[(size_t)cc * BATCH + b] = ctxv[cl][b] + pred;
  }
}

// ---------------------------------------------------------------------------
// Final prediction row: out[b][srow][.] = h @ w_fc^T + b_fc
// ---------------------------------------------------------------------------
__global__ __launch_bounds__(512, 2)
void fc_out(const float* __restrict__ h, const float* __restrict__ w_fc,
            const float* __restrict__ b_fc, float* __restrict__ out, int srow)
{
  __shared__ float red[8][2][64];
  const int tid = threadIdx.x;
  const int b  = tid & 63;
  const int ks = tid >> 6;
  const int cc0 = blockIdx.x * 2;
  const float* w0 = w_fc + (size_t)cc0 * HDIM + ks * 64;
  const float* w1 = w0 + HDIM;
  const float* hr = h + ks * 64 * BATCH;
  float p0 = 0.f, p1 = 0.f;
#pragma unroll 2
  for (int k = 0; k < 64; k += 4) {
    float4 wa = ld4(w0 + k), wb = ld4(w1 + k);
    float h0 = hr[(k + 0) * BATCH + b], h1 = hr[(k + 1) * BATCH + b];
    float h2 = hr[(k + 2) * BATCH + b], h3 = hr[(k + 3) * BATCH + b];
    p0 += wa.x * h0 + wa.y * h1 + wa.z * h2 + wa.w * h3;
    p1 += wb.x * h0 + wb.y * h1 + wb.z * h2 + wb.w * h3;
  }
  red[ks][0][b] = p0;
  red[ks][1][b] = p1;
  __syncthreads();
  if (tid < 128) {
    int cl = tid >> 6;
    int cc = cc0 + cl;
    float p = 0.f;
#pragma unroll
    for (int i = 0; i < 8; ++i) p += red[i][cl][b];
    out[((size_t)b * NAHEAD + srow) * HDIM + cc] = p + b_fc[cc];
  }
}

// ---------------------------------------------------------------------------
// x [B][T][I] -> xT [T][I][B] (LDS 64x64 tile per t)
// ---------------------------------------------------------------------------
__global__ __launch_bounds__(256)
void transpose_x(const float* __restrict__ x, float* __restrict__ xT)
{
  __shared__ float tile[64][65];
  const int t = blockIdx.x;
  const int lane = threadIdx.x & 63;
  const int w    = threadIdx.x >> 6;   // 0..3
#pragma unroll
  for (int ii = 0; ii < 16; ++ii) {
    int b = w * 16 + ii;
    tile[b][lane] = x[((size_t)b * TT + t) * IDIM + lane];   // lane over i
  }
  __syncthreads();
#pragma unroll
  for (int ii = 0; ii < 16; ++ii) {
    int i = w * 16 + ii;
    xT[((size_t)t * IDIM + i) * BATCH + lane] = tile[lane][i];  // lane over b
  }
}

// ---------------------------------------------------------------------------
extern "C" void kernel_launch(void* const* d_in, const int* in_sizes, int n_in,
                              void* d_out, int out_size, void* d_ws, size_t ws_size,
                              hipStream_t stream) {
  const float* x     = (const float*)d_in[0];
  const float* w_ih0 = (const float*)d_in[1];
  const float* w_hh0 = (const float*)d_in[2];
  const float* b_ih0 = (const float*)d_in[3];
  const float* b_hh0 = (const float*)d_in[4];
  const float* w_ih1 = (const float*)d_in[5];
  const float* w_hh1 = (const float*)d_in[6];
  const float* b_ih1 = (const float*)d_in[7];
  const float* b_hh1 = (const float*)d_in[8];
  const float* w_ihd = (const float*)d_in[9];
  const float* w_hhd = (const float*)d_in[10];
  const float* b_ihd = (const float*)d_in[11];
  const float* b_hhd = (const float*)d_in[12];
  const float* w_fc  = (const float*)d_in[13];
  const float* b_fc  = (const float*)d_in[14];
  float* out = (float*)d_out;

  char* ws = (char*)d_ws;
  size_t off = 0;
  auto alloc = [&](size_t bytes) -> void* {
    void* p = ws + off;
    off += (bytes + 255) & ~(size_t)255;
    return p;
  };

  float* cst0 = (float*)alloc((size_t)HB * 4);            // zero
  float* cst1 = (float*)alloc((size_t)HB * 4);            // zero
  float* seq0 = (float*)alloc((size_t)(TT + 1) * HB * 4); // slot0 zero
  float* enc  = (float*)alloc((size_t)(TT + 1) * HB * 4); // slot0 zero
  float* xT   = (float*)alloc((size_t)TT * IDIM * BATCH * 4);
  float* scores = (float*)alloc((size_t)TT * BATCH * 4);
  float* xi     = (float*)alloc((size_t)HB * 4);
  float* hdec   = (float*)alloc((size_t)2 * HB * 4);
  (void)ws_size; (void)in_sizes; (void)n_in; (void)out_size;

  // zero the state / t=-1 slots (cst0,cst1 contiguous with seq0 slot0)
  hipMemsetAsync(cst0, 0, (size_t)HB * 4 * 2, stream);
  hipMemsetAsync(seq0, 0, (size_t)HB * 4, stream);
  hipMemsetAsync(enc,  0, (size_t)HB * 4, stream);

  transpose_x<<<TT, 256, 0, stream>>>(x, xT);

  // 513 pipelined launches: L0 step t + L1 step t-1 per kernel.
  for (int t = 0; t <= TT; ++t) {
    lstm_step<<<256, 1024, 0, stream>>>(
        t, xT, w_ih0, w_hh0, b_ih0, b_hh0,
        w_ih1, w_hh1, b_ih1, b_hh1, seq0, enc, cst0, cst1);
  }

  // decoder: h state starts at h1_{511} = enc[512]; c continues in cst1.
  const float* h_cur = enc + (size_t)TT * HB;
  for (int s = 0; s < NAHEAD; ++s) {
    attn_scores<<<256, 512, 0, stream>>>(enc, h_cur, scores);
    attn_ctx<<<256, 512, 0, stream>>>(enc, scores, h_cur, w_fc, b_fc,
                                      xi, out, s);
    float* h_nxt = hdec + (size_t)(s & 1) * HB;
    dec_gates<<<256, 1024, 0, stream>>>(xi, h_cur, w_ihd, w_hhd,
                                        b_ihd, b_hhd, cst1, h_nxt);
    h_cur = h_nxt;
  }
  fc_out<<<256, 512, 0, stream>>>(h_cur, w_fc, b_fc, out, NAHEAD - 1);
}

// Round 7
// 17083.620 us; speedup vs baseline: 3.5666x; 1.2404x over previous
//
#include <hip/hip_runtime.h>

#define BATCH  64
#define TT     512
#define IDIM   64
#define HDIM   512
#define NAHEAD 24
#define HB     (HDIM * BATCH)

__device__ __forceinline__ float4 ld4(const float* p) {
  return *reinterpret_cast<const float4*>(p);
}
__device__ __forceinline__ float sigm(float x) { return 1.0f / (1.0f + expf(-x)); }

// ---------------------------------------------------------------------------
// LSTM cell for 2 h-cols {j0, j0+1}, all 64 batch rows. 1024 threads.
// Thread = (b = tid&63, ks = tid>>6 in 0..15). Each thread: 8 accumulators
// (2 cols x 4 gates) over its K/16 slice; inputs loaded ONCE per k; weights
// wave-uniform (ks is per-wave constant -> scalarizable). Partials reduced
// via LDS [8][64][17] (stride 17: conflict-free).
// sm needs 8*64*17 + 8*64 floats (= 36 KB). Ends with __syncthreads.
// ---------------------------------------------------------------------------
template <int DIN0>
__device__ __forceinline__ void cell_tile2(
    int j0, const float* __restrict__ in0,             // [DIN0][B]
    const float* __restrict__ h_in,                    // [512][B]
    const float* __restrict__ w_ih,                    // [4H][DIN0]
    const float* __restrict__ w_hh,                    // [4H][512]
    const float* __restrict__ b_ih, const float* __restrict__ b_hh,
    float* __restrict__ c_state,                       // [512][B]
    float* __restrict__ h_out,                         // [512][B]
    float* __restrict__ sm)
{
  const int tid = threadIdx.x;
  const int b  = tid & 63;
  const int ks = tid >> 6;                 // 0..15, uniform per wave
  constexpr int K  = DIN0 + HDIM;
  constexpr int KS = K / 16;               // 36 (L0) / 64 (L1), %4 == 0
  const int k0 = ks * KS, k1 = k0 + KS;
  // split this thread's k-range at the DIN0 boundary (all bounds %4 == 0)
  const int a0 = (k0 < DIN0) ? k0 : DIN0;
  const int a1 = (k1 < DIN0) ? k1 : DIN0;
  const int c0 = (k0 > DIN0) ? k0 - DIN0 : 0;
  const int c1 = (k1 > DIN0) ? k1 - DIN0 : 0;

  // d = gate*2 + col: row r(d) = (d>>1)*HDIM + j0 + (d&1)
  const float* wi = w_ih + (size_t)j0 * DIN0;
  const float* wh = w_hh + (size_t)j0 * HDIM;

  float acc[8] = {0.f, 0.f, 0.f, 0.f, 0.f, 0.f, 0.f, 0.f};

#pragma unroll 2
  for (int k = a0; k < a1; k += 4) {       // input-projection slice
    float x0 = in0[(k + 0) * BATCH + b];
    float x1 = in0[(k + 1) * BATCH + b];
    float x2 = in0[(k + 2) * BATCH + b];
    float x3 = in0[(k + 3) * BATCH + b];
#pragma unroll
    for (int d = 0; d < 8; ++d) {
      float4 w = ld4(wi + (size_t)((d >> 1) * HDIM + (d & 1)) * DIN0 + k);
      acc[d] += x0 * w.x + x1 * w.y + x2 * w.z + x3 * w.w;
    }
  }
#pragma unroll 2
  for (int k = c0; k < c1; k += 4) {       // recurrent slice
    float h0 = h_in[(k + 0) * BATCH + b];
    float h1 = h_in[(k + 1) * BATCH + b];
    float h2 = h_in[(k + 2) * BATCH + b];
    float h3 = h_in[(k + 3) * BATCH + b];
#pragma unroll
    for (int d = 0; d < 8; ++d) {
      float4 w = ld4(wh + (size_t)((d >> 1) * HDIM + (d & 1)) * HDIM + k);
      acc[d] += h0 * w.x + h1 * w.y + h2 * w.z + h3 * w.w;
    }
  }

  float* gl = sm + 8 * 64 * 17;
#pragma unroll
  for (int d = 0; d < 8; ++d) sm[(d * 64 + b) * 17 + ks] = acc[d];
  __syncthreads();

  if (tid < 512) {                          // reduce 16 partials per dot
    const int dd = tid >> 6, bb = tid & 63;
    float s = 0.f;
#pragma unroll
    for (int i = 0; i < 16; ++i) s += sm[(dd * 64 + bb) * 17 + i];
    const int r = (dd >> 1) * HDIM + j0 + (dd & 1);
    gl[dd * 64 + bb] = s + b_ih[r] + b_hh[r];
  }
  __syncthreads();

  if (tid < 128) {                          // cell update for (col, b)
    const int bb = tid & 63, cl = tid >> 6;
    const int jc = j0 + cl;
    float gi = gl[(0 + cl) * 64 + bb];      // gate order i,f,g,o
    float gf = gl[(2 + cl) * 64 + bb];
    float gg = gl[(4 + cl) * 64 + bb];
    float go = gl[(6 + cl) * 64 + bb];
    float cold = c_state[(size_t)jc * BATCH + bb];
    float cn = sigm(gf) * cold + sigm(gi) * tanhf(gg);
    float hn = sigm(go) * tanhf(cn);
    c_state[(size_t)jc * BATCH + bb] = cn;
    h_out[(size_t)jc * BATCH + bb] = hn;
  }
  __syncthreads();   // smem safe for reuse by a second phase
}

// ---------------------------------------------------------------------------
// One pipeline step: L0 at time t (if t<T) and L1 at time t-1 (if t>=1).
// seq0[tau] = h0_{tau-1} (slot0 = zeros); enc[tau] = h1_{tau-1} (slot0 = 0).
// No intra-kernel cross-WG dependency: L0 writes seq0[t+1], L1 reads seq0[t].
// ---------------------------------------------------------------------------
__global__ __launch_bounds__(1024, 1)
void lstm_step(int t,
               const float* __restrict__ xT,    // [T][I][B]
               const float* __restrict__ w_ih0, const float* __restrict__ w_hh0,
               const float* __restrict__ b_ih0, const float* __restrict__ b_hh0,
               const float* __restrict__ w_ih1, const float* __restrict__ w_hh1,
               const float* __restrict__ b_ih1, const float* __restrict__ b_hh1,
               float* __restrict__ seq0,        // [T+1][H][B]
               float* __restrict__ enc,         // [T+1][H][B]
               float* __restrict__ cst0, float* __restrict__ cst1)  // [H][B]
{
  __shared__ float sm[8 * 64 * 17 + 8 * 64];
  const int j0 = blockIdx.x * 2;
  if (t < TT)
    cell_tile2<IDIM>(j0, xT + (size_t)t * IDIM * BATCH,
                     seq0 + (size_t)t * HB,
                     w_ih0, w_hh0, b_ih0, b_hh0,
                     cst0, seq0 + (size_t)(t + 1) * HB, sm);
  if (t >= 1)
    cell_tile2<HDIM>(j0, seq0 + (size_t)t * HB,
                     enc + (size_t)(t - 1) * HB,
                     w_ih1, w_hh1, b_ih1, b_hh1,
                     cst1, enc + (size_t)t * HB, sm);
}

// ---------------------------------------------------------------------------
// Decoder gate step (xi ; h_cur) -> h_out, c in place. 256 WGs x 1024.
// ---------------------------------------------------------------------------
__global__ __launch_bounds__(1024, 1)
void dec_gates(const float* __restrict__ xi, const float* __restrict__ h_cur,
               const float* __restrict__ w_ih, const float* __restrict__ w_hh,
               const float* __restrict__ b_ih, const float* __restrict__ b_hh,
               float* __restrict__ cst, float* __restrict__ h_out)
{
  __shared__ float sm[8 * 64 * 17 + 8 * 64];
  cell_tile2<HDIM>(blockIdx.x * 2, xi, h_cur, w_ih, w_hh, b_ih, b_hh,
                   cst, h_out, sm);
}

// ---------------------------------------------------------------------------
// scores[t][b] = dot(enc_out[t][.][b], h_cur[.][b]); WG handles 2 t's.
// ---------------------------------------------------------------------------
__global__ __launch_bounds__(512, 2)
void attn_scores(const float* __restrict__ enc,   // [T+1][H][B]
                 const float* __restrict__ h_cur, // [H][B]
                 float* __restrict__ scores)      // [T][B]
{
  __shared__ float red[2][8][64];
  const int tid = threadIdx.x;
  const int b  = tid & 63;
  const int ks = tid >> 6;              // 0..7, k-slice of 64
  const int t0 = blockIdx.x * 2;
  const float* e0 = enc + (size_t)(t0 + 1) * HB + ks * 64 * BATCH;
  const float* e1 = e0 + HB;
  const float* hr = h_cur + ks * 64 * BATCH;
  float a0 = 0.f, a1 = 0.f;
#pragma unroll 4
  for (int k = 0; k < 64; ++k) {
    float hv = hr[k * BATCH + b];
    a0 += hv * e0[k * BATCH + b];
    a1 += hv * e1[k * BATCH + b];
  }
  red[0][ks][b] = a0;
  red[1][ks][b] = a1;
  __syncthreads();
  if (tid < 128) {
    int tl = tid >> 6;
    float s = 0.f;
#pragma unroll
    for (int i = 0; i < 8; ++i) s += red[tl][i][b];
    scores[(size_t)(t0 + tl) * BATCH + b] = s;
  }
}

// ---------------------------------------------------------------------------
// Per step s: redundant per-WG softmax over scores, ctx for 2 h-cols,
// pred_{s-1} = h_cur @ w_fc^T (rows = same 2 cols) -> out row s-1,
// xi = ctx + pred_{s-1} (dec_in). s==0: dec_in = 0, no out write.
// ---------------------------------------------------------------------------
__global__ __launch_bounds__(512, 2)
void attn_ctx(const float* __restrict__ enc,     // [T+1][H][B]
              const float* __restrict__ scores,  // [T][B]
              const float* __restrict__ h_cur,   // [H][B]
              const float* __restrict__ w_fc, const float* __restrict__ b_fc,
              float* __restrict__ xi,            // [H][B]
              float* __restrict__ out,           // [B][24][C]
              int s)
{
  __shared__ float red[8][2][64];
  __shared__ float mz[2][64];
  __shared__ float ctxv[2][64];
  const int tid = threadIdx.x;
  const int b  = tid & 63;
  const int ts = tid >> 6;              // 0..7, t-slice of 64
  const int hc0 = blockIdx.x * 2;

  // softmax stats (redundant per WG — avoids a device-wide barrier)
  float m = -1e30f;
  for (int t = ts * 64; t < ts * 64 + 64; ++t)
    m = fmaxf(m, scores[(size_t)t * BATCH + b]);
  red[ts][0][b] = m;
  __syncthreads();
  if (tid < 64) {
    float mm = red[0][0][b];
#pragma unroll
    for (int i = 1; i < 8; ++i) mm = fmaxf(mm, red[i][0][b]);
    mz[0][b] = mm;
  }
  __syncthreads();
  m = mz[0][b];
  float z = 0.f;
  for (int t = ts * 64; t < ts * 64 + 64; ++t)
    z += expf(scores[(size_t)t * BATCH + b] - m);
  red[ts][1][b] = z;
  __syncthreads();
  if (tid < 64) {
    float zz = 0.f;
#pragma unroll
    for (int i = 0; i < 8; ++i) zz += red[i][1][b];
    mz[1][b] = 1.f / zz;
  }
  __syncthreads();
  const float rZ = mz[1][b];

  // ctx for cols hc0, hc0+1 over this thread's t-slice
  float a0 = 0.f, a1 = 0.f;
  const float* eb = enc + HB + (size_t)hc0 * BATCH + b;
  for (int t = ts * 64; t < ts * 64 + 64; ++t) {
    float p = expf(scores[(size_t)t * BATCH + b] - m) * rZ;
    a0 += p * eb[(size_t)t * HB];
    a1 += p * eb[(size_t)t * HB + BATCH];
  }
  __syncthreads();
  red[ts][0][b] = a0;
  red[ts][1][b] = a1;
  __syncthreads();
  if (tid < 128) {
    int cl = tid >> 6;
    float c = 0.f;
#pragma unroll
    for (int i = 0; i < 8; ++i) c += red[i][cl][b];
    ctxv[cl][b] = c;
  }

  // pred_{s-1} for rows hc0, hc0+1 (k-sliced)
  float p0 = 0.f, p1 = 0.f;
  if (s >= 1) {
    const float* w0 = w_fc + (size_t)hc0 * HDIM + ts * 64;
    const float* w1 = w0 + HDIM;
    const float* hr = h_cur + ts * 64 * BATCH;
#pragma unroll 2
    for (int k = 0; k < 64; k += 4) {
      float4 wa = ld4(w0 + k), wb = ld4(w1 + k);
      float h0 = hr[(k + 0) * BATCH + b], h1 = hr[(k + 1) * BATCH + b];
      float h2 = hr[(k + 2) * BATCH + b], h3 = hr[(k + 3) * BATCH + b];
      p0 += wa.x * h0 + wa.y * h1 + wa.z * h2 + wa.w * h3;
      p1 += wb.x * h0 + wb.y * h1 + wb.z * h2 + wb.w * h3;
    }
  }
  __syncthreads();
  red[ts][0][b] = p0;
  red[ts][1][b] = p1;
  __syncthreads();
  if (tid < 128) {
    int cl = tid >> 6;
    int cc = hc0 + cl;
    float pred = 0.f;
    if (s >= 1) {
#pragma unroll
      for (int i = 0; i < 8; ++i) pred += red[i][cl][b];
      pred += b_fc[cc];
      out[((size_t)b * NAHEAD + (s - 1)) * HDIM + cc] = pred;
    }
    xi[(size_t)cc * BATCH + b] = ctxv[cl][b] + pred;
  }
}

// ---------------------------------------------------------------------------
// Final prediction row: out[b][srow][.] = h @ w_fc^T + b_fc
// ---------------------------------------------------------------------------
__global__ __launch_bounds__(512, 2)
void fc_out(const float* __restrict__ h, const float* __restrict__ w_fc,
            const float* __restrict__ b_fc, float* __restrict__ out, int srow)
{
  __shared__ float red[8][2][64];
  const int tid = threadIdx.x;
  const int b  = tid & 63;
  const int ks = tid >> 6;
  const int cc0 = blockIdx.x * 2;
  const float* w0 = w_fc + (size_t)cc0 * HDIM + ks * 64;
  const float* w1 = w0 + HDIM;
  const float* hr = h + ks * 64 * BATCH;
  float p0 = 0.f, p1 = 0.f;
#pragma unroll 2
  for (int k = 0; k < 64; k += 4) {
    float4 wa = ld4(w0 + k), wb = ld4(w1 + k);
    float h0 = hr[(k + 0) * BATCH + b], h1 = hr[(k + 1) * BATCH + b];
    float h2 = hr[(k + 2) * BATCH + b], h3 = hr[(k + 3) * BATCH + b];
    p0 += wa.x * h0 + wa.y * h1 + wa.z * h2 + wa.w * h3;
    p1 += wb.x * h0 + wb.y * h1 + wb.z * h2 + wb.w * h3;
  }
  red[ks][0][b] = p0;
  red[ks][1][b] = p1;
  __syncthreads();
  if (tid < 128) {
    int cl = tid >> 6;
    int cc = cc0 + cl;
    float p = 0.f;
#pragma unroll
    for (int i = 0; i < 8; ++i) p += red[i][cl][b];
    out[((size_t)b * NAHEAD + srow) * HDIM + cc] = p + b_fc[cc];
  }
}

// ---------------------------------------------------------------------------
// x [B][T][I] -> xT [T][I][B] (LDS 64x64 tile per t)
// ---------------------------------------------------------------------------
__global__ __launch_bounds__(256)
void transpose_x(const float* __restrict__ x, float* __restrict__ xT)
{
  __shared__ float tile[64][65];
  const int t = blockIdx.x;
  const int lane = threadIdx.x & 63;
  const int w    = threadIdx.x >> 6;   // 0..3
#pragma unroll
  for (int ii = 0; ii < 16; ++ii) {
    int b = w * 16 + ii;
    tile[b][lane] = x[((size_t)b * TT + t) * IDIM + lane];   // lane over i
  }
  __syncthreads();
#pragma unroll
  for (int ii = 0; ii < 16; ++ii) {
    int i = w * 16 + ii;
    xT[((size_t)t * IDIM + i) * BATCH + lane] = tile[lane][i];  // lane over b
  }
}

// ---------------------------------------------------------------------------
extern "C" void kernel_launch(void* const* d_in, const int* in_sizes, int n_in,
                              void* d_out, int out_size, void* d_ws, size_t ws_size,
                              hipStream_t stream) {
  const float* x     = (const float*)d_in[0];
  const float* w_ih0 = (const float*)d_in[1];
  const float* w_hh0 = (const float*)d_in[2];
  const float* b_ih0 = (const float*)d_in[3];
  const float* b_hh0 = (const float*)d_in[4];
  const float* w_ih1 = (const float*)d_in[5];
  const float* w_hh1 = (const float*)d_in[6];
  const float* b_ih1 = (const float*)d_in[7];
  const float* b_hh1 = (const float*)d_in[8];
  const float* w_ihd = (const float*)d_in[9];
  const float* w_hhd = (const float*)d_in[10];
  const float* b_ihd = (const float*)d_in[11];
  const float* b_hhd = (const float*)d_in[12];
  const float* w_fc  = (const float*)d_in[13];
  const float* b_fc  = (const float*)d_in[14];
  float* out = (float*)d_out;

  char* ws = (char*)d_ws;
  size_t off = 0;
  auto alloc = [&](size_t bytes) -> void* {
    void* p = ws + off;
    off += (bytes + 255) & ~(size_t)255;
    return p;
  };

  float* cst0 = (float*)alloc((size_t)HB * 4);            // zero
  float* cst1 = (float*)alloc((size_t)HB * 4);            // zero
  float* seq0 = (float*)alloc((size_t)(TT + 1) * HB * 4); // slot0 zero
  float* enc  = (float*)alloc((size_t)(TT + 1) * HB * 4); // slot0 zero
  float* xT   = (float*)alloc((size_t)TT * IDIM * BATCH * 4);
  float* scores = (float*)alloc((size_t)TT * BATCH * 4);
  float* xi     = (float*)alloc((size_t)HB * 4);
  float* hdec   = (float*)alloc((size_t)2 * HB * 4);
  (void)ws_size; (void)in_sizes; (void)n_in; (void)out_size;

  // zero the state / t=-1 slots (cst0,cst1 contiguous)
  hipMemsetAsync(cst0, 0, (size_t)HB * 4 * 2, stream);
  hipMemsetAsync(seq0, 0, (size_t)HB * 4, stream);
  hipMemsetAsync(enc,  0, (size_t)HB * 4, stream);

  transpose_x<<<TT, 256, 0, stream>>>(x, xT);

  // 513 pipelined launches: L0 step t + L1 step t-1 per kernel.
  for (int t = 0; t <= TT; ++t) {
    lstm_step<<<256, 1024, 0, stream>>>(
        t, xT, w_ih0, w_hh0, b_ih0, b_hh0,
        w_ih1, w_hh1, b_ih1, b_hh1, seq0, enc, cst0, cst1);
  }

  // decoder: h state starts at h1_{511} = enc[512]; c continues in cst1.
  const float* h_cur = enc + (size_t)TT * HB;
  for (int s = 0; s < NAHEAD; ++s) {
    attn_scores<<<256, 512, 0, stream>>>(enc, h_cur, scores);
    attn_ctx<<<256, 512, 0, stream>>>(enc, scores, h_cur, w_fc, b_fc,
                                      xi, out, s);
    float* h_nxt = hdec + (size_t)(s & 1) * HB;
    dec_gates<<<256, 1024, 0, stream>>>(xi, h_cur, w_ihd, w_hhd,
                                        b_ihd, b_hhd, cst1, h_nxt);
    h_cur = h_nxt;
  }
  fc_out<<<256, 512, 0, stream>>>(h_cur, w_fc, b_fc, out, NAHEAD - 1);
}